// Round 12
// baseline (886.575 us; speedup 1.0000x reference)
//
#include <hip/hip_runtime.h>

#define NPIX 4096
#define CHN  64

typedef __attribute__((ext_vector_type(8))) short short8;
typedef __attribute__((ext_vector_type(8))) unsigned short ushort8;
typedef __attribute__((ext_vector_type(4))) unsigned short ushort4v;
typedef __attribute__((ext_vector_type(4))) float f32x4;
typedef __attribute__((ext_vector_type(16))) float f32x16;
typedef __attribute__((ext_vector_type(4))) unsigned int uint4v;

__device__ __forceinline__ float lrelu_(float x){ return x >= 0.f ? x : 0.01f*x; }

__device__ __forceinline__ unsigned short f2bf(float x){
  union { float f; unsigned u; } v; v.f = x;
  unsigned r = v.u + 0x7FFF + ((v.u >> 16) & 1);
  return (unsigned short)(r >> 16);
}
__device__ __forceinline__ float bf2f(unsigned short h){
  union { unsigned u; float f; } v; v.u = ((unsigned)h) << 16;
  return v.f;
}
__device__ __forceinline__ float asf_(unsigned u){
  union { unsigned u; float f; } v; v.u = u; return v.f;
}

// ---------------- positional embedding table [32][4096] ----------------
__global__ void pos_kernel(float* __restrict__ pos){
  int idx = blockIdx.x*256 + threadIdx.x;       // 32*4096 = 131072
  int c = idx >> 12;
  int n = idx & (NPIX-1);
  int bcoord = (c < 16) ? (n >> 6) : (n & 63);
  int a = (c < 16) ? c : (c - 16);
  int flat = a*64 + bcoord;                     // index into pe flat [64*16]
  int p = flat >> 4;
  int j = flat & 15;
  float val = 0.f;
  if (p != 0){
    float ex = (float)(j & ~1) * (1.f/16.f);
    float w = powf(10000.f, -ex);
    float ang = (float)p * w;
    val = (j & 1) ? cosf(ang) : sinf(ang);
  }
  pos[idx] = val;
}

// ---------------- weight transpose ----------------
// wt: q [l][i][o] 49152 | fk/ck/fv/cv [l][i][o] 81920 each | conv [tap75][o64] 4800
__global__ void wtr_kernel(const float* __restrict__ qw, const float* __restrict__ fkw,
                           const float* __restrict__ ckw, const float* __restrict__ fvw,
                           const float* __restrict__ cvw, const float* __restrict__ convw,
                           float* __restrict__ wt){
  int idx = blockIdx.x*256 + threadIdx.x;
  if (idx >= 381632) return;
  if (idx < 49152){
    int l = idx / 6144, r = idx % 6144, i = r >> 6, o = r & 63;
    wt[idx] = qw[(l*64 + o)*96 + i];
  } else if (idx < 376832){
    int e = idx - 49152;
    int mat = e / 81920, r = e % 81920;
    int l = r / 10240, rr = r % 10240, i = rr >> 6, o = rr & 63;
    const float* src = (mat==0) ? fkw : (mat==1) ? ckw : (mat==2) ? fvw : cvw;
    wt[idx] = src[(l*64 + o)*160 + i];
  } else {
    int e = idx - 376832;          // [tap][o], tap = ci*25 + (ky*5+kx)
    int o = e & 63, tap = e >> 6;
    int ci = tap / 25, r = tap % 25;
    wt[idx] = convw[(o*3 + ci)*25 + r];
  }
}

// ---------------- masked causal 5x5 conv (input layer) ----------------
__global__ __launch_bounds__(256) void conv_in_kernel(const float* __restrict__ x,
                                                      const float* __restrict__ cwt,
                                                      const float* __restrict__ cb,
                                                      float* __restrict__ out){
  int t = threadIdx.x;
  int o = t & 63;
  int sub = t >> 6;
  int bid = blockIdx.x;
  int b = bid >> 10;
  int n = ((bid & 1023) << 2) + sub;
  int y = n >> 6, xx = n & 63;
  float acc = cb[o];
  #pragma unroll
  for (int ci=0; ci<3; ++ci){
    const float* xp = x + ((b*3+ci)<<12);
    #pragma unroll
    for (int ky=0; ky<3; ++ky){
      int yy = y + ky - 2;
      if (yy < 0) continue;
      int nk = (ky==2) ? 2 : 5;
      #pragma unroll
      for (int kx=0; kx<5; ++kx){
        if (kx >= nk) break;
        int xc = xx + kx - 2;
        if (xc < 0 || xc > 63) continue;
        acc += xp[(yy<<6) + xc] * cwt[(ci*25 + ky*5 + kx)*64 + o];
      }
    }
  }
  out[(b*CHN+o)*NPIX + n] = acc;
}

// ---------------- batch-norm stats (conv path only) ----------------
__global__ __launch_bounds__(1024) void bn_stats_kernel(const float* __restrict__ xin,
                                                        float* __restrict__ stats){
  int c = blockIdx.x;
  int t = threadIdx.x;
  float s = 0.f, ss = 0.f;
  #pragma unroll
  for (int it=0; it<8; ++it){
    int idx = t + it*1024;
    float v = xin[(((idx>>12))*CHN + c)*NPIX + (idx & (NPIX-1))];
    s += v; ss += v*v;
  }
  #pragma unroll
  for (int o=1; o<64; o<<=1){ s += __shfl_xor(s,o); ss += __shfl_xor(ss,o); }
  __shared__ float ps[16], pq[16];
  if ((t & 63) == 0){ ps[t>>6] = s; pq[t>>6] = ss; }
  __syncthreads();
  if (t == 0){
    float S=0.f, Q=0.f;
    #pragma unroll
    for (int i=0;i<16;++i){ S += ps[i]; Q += pq[i]; }
    float mu = S*(1.f/8192.f);
    float var = Q*(1.f/8192.f) - mu*mu;
    var = fmaxf(var, 0.f);
    stats[c*2]   = mu;
    stats[c*2+1] = rsqrtf(var + 1e-5f);
  }
}

// ---------------- BN apply + LeakyReLU (conv path) ----------------
__global__ void bn_apply_kernel(const float* __restrict__ xin, const float* __restrict__ stats,
                                const float* __restrict__ g, const float* __restrict__ bb,
                                float* __restrict__ hout){
  int idx = blockIdx.x*256 + threadIdx.x;
  int e = idx << 2;
  int c = (e >> 12) & 63;
  float mu = stats[c*2], rstd = stats[c*2+1];
  float gain = g[c]*rstd;
  float beta = bb[c] - gain*mu;
  float4 v = *(const float4*)(xin + e);
  float4 r;
  r.x = lrelu_(gain*v.x + beta);
  r.y = lrelu_(gain*v.y + beta);
  r.z = lrelu_(gain*v.z + beta);
  r.w = lrelu_(gain*v.w + beta);
  *(float4*)(hout + e) = r;
}

// ---------------- BN apply + LeakyReLU from per-seg partials (in-place) ---
__global__ __launch_bounds__(256) void bn_apply2_kernel(float* __restrict__ hbuf,
                                                        const float* __restrict__ psum,
                                                        const float* __restrict__ psq,
                                                        const float* __restrict__ g,
                                                        const float* __restrict__ bb){
  int bid = blockIdx.x;
  int ebase = bid << 10;
  int c = (ebase >> 12) & 63;
  int t = threadIdx.x;
  float s = psum[c*256 + t];
  float q = psq[c*256 + t];
  #pragma unroll
  for (int o=1; o<64; o<<=1){ s += __shfl_xor(s,o); q += __shfl_xor(q,o); }
  __shared__ float as[4], aq[4];
  if ((t & 63) == 0){ as[t>>6] = s; aq[t>>6] = q; }
  __syncthreads();
  float S = as[0]+as[1]+as[2]+as[3];
  float Q = aq[0]+aq[1]+aq[2]+aq[3];
  float mu = S*(1.f/8192.f);
  float var = fmaxf(Q*(1.f/8192.f) - mu*mu, 0.f);
  float rstd = rsqrtf(var + 1e-5f);
  float gain = g[c]*rstd;
  float beta = bb[c] - gain*mu;
  float4 v = *(const float4*)(hbuf + ebase + t*4);
  float4 r;
  r.x = lrelu_(gain*v.x + beta);
  r.y = lrelu_(gain*v.y + beta);
  r.z = lrelu_(gain*v.z + beta);
  r.w = lrelu_(gain*v.w + beta);
  *(float4*)(hbuf + ebase + t*4) = r;
}

// ---------------- five 1x1 convs, section-split ----------------
// grid 1536 = sec(3) x b(2) x tile(256 of 16 px); block 256 = 4 waves x 4 px.
__global__ __launch_bounds__(256) void cv1_kernel(
    const float* __restrict__ hbuf, const float* __restrict__ pos,
    const float* __restrict__ kold, const float* __restrict__ vold,
    const float* __restrict__ qwt,
    const float* __restrict__ fkwt, const float* __restrict__ ckwt,
    const float* __restrict__ fvwt, const float* __restrict__ cvwt,
    const float* __restrict__ qbi,  const float* __restrict__ fkb,
    const float* __restrict__ ckb,  const float* __restrict__ fvb,
    const float* __restrict__ cvb,
    unsigned short* __restrict__ qh, unsigned short* __restrict__ ql,
    float* __restrict__ knew, unsigned short* __restrict__ khn, unsigned short* __restrict__ kln,
    float* __restrict__ vnew, unsigned short* __restrict__ vhTn, unsigned short* __restrict__ vlTn)
{
  int t = threadIdx.x;
  int o  = t & 63;
  int wv = t >> 6;                      // 0..3
  int sec  = blockIdx.x >> 9;           // 0,1,2
  int bid  = blockIdx.x & 511;
  int b    = bid >> 8;
  int tile = bid & 255;
  int n0 = tile*16 + wv*4;

  const float* hb = hbuf + b*CHN*NPIX + n0;
  const float* pb = pos + n0;

  auto load4 = [&](const float* p, float* dst){
    float4 a = *(const float4*)p;
    dst[0]=a.x; dst[1]=a.y; dst[2]=a.z; dst[3]=a.w;
  };

  float x[4];
  long obase = (long)(b*CHN+o)*NPIX + n0;
  size_t nbase = ((size_t)b*NPIX + n0)*64 + o;

  if (sec == 0){
    float aq[4];
    float bias = qbi[o];
    #pragma unroll
    for (int j=0;j<4;++j) aq[j]=bias;
    #pragma unroll 4
    for (int i=0;i<64;++i){
      load4(hb + i*NPIX, x);
      float w = qwt[i*64 + o];
      #pragma unroll
      for (int j=0;j<4;++j) aq[j] += w*x[j];
    }
    #pragma unroll 4
    for (int i=0;i<32;++i){
      load4(pb + i*NPIX, x);
      float w = qwt[(64+i)*64 + o];
      #pragma unroll
      for (int j=0;j<4;++j) aq[j] += w*x[j];
    }
    const float QS = 0.125f * 1.4426950408889634f;
    #pragma unroll
    for (int j=0;j<4;++j){
      float v = lrelu_(aq[j]) * QS;
      unsigned short hb16 = f2bf(v);
      qh[nbase + (size_t)j*64] = hb16;
      ql[nbase + (size_t)j*64] = f2bf(v - bf2f(hb16));
    }
  } else if (sec == 1){
    const float* kb = kold + b*CHN*NPIX + n0;
    float af[4], ac[4];
    float bf = fkb[o], bc = ckb[o];
    #pragma unroll
    for (int j=0;j<4;++j){ af[j]=bf; ac[j]=bc; }
    #pragma unroll 4
    for (int i=0;i<64;++i){
      load4(hb + i*NPIX, x);
      float wf = fkwt[i*64+o], wc = ckwt[i*64+o];
      #pragma unroll
      for (int j=0;j<4;++j){ af[j] += wf*x[j]; ac[j] += wc*x[j]; }
    }
    #pragma unroll 4
    for (int i=0;i<32;++i){
      load4(pb + i*NPIX, x);
      float wf = fkwt[(64+i)*64+o], wc = ckwt[(64+i)*64+o];
      #pragma unroll
      for (int j=0;j<4;++j){ af[j] += wf*x[j]; ac[j] += wc*x[j]; }
    }
    #pragma unroll 4
    for (int i=0;i<64;++i){
      load4(kb + i*NPIX, x);
      float wf = fkwt[(96+i)*64+o], wc = ckwt[(96+i)*64+o];
      #pragma unroll
      for (int j=0;j<4;++j){ af[j] += wf*x[j]; ac[j] += wc*x[j]; }
    }
    float kv[4];
    load4(kb + o*NPIX, kv);
    #pragma unroll
    for (int j=0;j<4;++j){
      float fk = 1.f/(1.f+__expf(-af[j]));
      float kn = fk*kv[j] + lrelu_(ac[j]);
      knew[obase+j] = kn;
      unsigned short hb16 = f2bf(kn);
      khn[nbase + (size_t)j*64] = hb16;
      kln[nbase + (size_t)j*64] = f2bf(kn - bf2f(hb16));
    }
  } else {
    const float* vb = vold + b*CHN*NPIX + n0;
    float af[4], ac[4];
    float bf = fvb[o], bc = cvb[o];
    #pragma unroll
    for (int j=0;j<4;++j){ af[j]=bf; ac[j]=bc; }
    #pragma unroll 4
    for (int i=0;i<64;++i){
      load4(hb + i*NPIX, x);
      float wf = fvwt[i*64+o], wc = cvwt[i*64+o];
      #pragma unroll
      for (int j=0;j<4;++j){ af[j] += wf*x[j]; ac[j] += wc*x[j]; }
    }
    #pragma unroll 4
    for (int i=0;i<32;++i){
      load4(pb + i*NPIX, x);
      float wf = fvwt[(64+i)*64+o], wc = cvwt[(64+i)*64+o];
      #pragma unroll
      for (int j=0;j<4;++j){ af[j] += wf*x[j]; ac[j] += wc*x[j]; }
    }
    #pragma unroll 4
    for (int i=0;i<64;++i){
      load4(vb + i*NPIX, x);
      float wf = fvwt[(96+i)*64+o], wc = cvwt[(96+i)*64+o];
      #pragma unroll
      for (int j=0;j<4;++j){ af[j] += wf*x[j]; ac[j] += wc*x[j]; }
    }
    float vv[4];
    load4(vb + o*NPIX, vv);
    ushort4v vph, vpl;
    #pragma unroll
    for (int j=0;j<4;++j){
      float fv = 1.f/(1.f+__expf(-af[j]));
      float vn = fv*vv[j] + lrelu_(ac[j]);
      vnew[obase+j] = vn;
      unsigned short hb16 = f2bf(vn);
      vph[j] = hb16;
      vpl[j] = f2bf(vn - bf2f(hb16));
    }
    *(ushort4v*)(vhTn + ((size_t)(b*CHN+o))*NPIX + n0) = vph;
    *(ushort4v*)(vlTn + ((size_t)(b*CHN+o))*NPIX + n0) = vpl;
  }
}

// pack one f32x16 C-fragment into bf16 hi/lo quad-pairs (per a=0..3: 2 u32 each)
__device__ __forceinline__ void pack_sf(const f32x16& sfv, unsigned (&ph)[4][2],
                                        unsigned (&pl)[4][2]){
  #pragma unroll
  for (int a=0; a<4; ++a){
    unsigned h0, h1;
    asm("v_cvt_pk_bf16_f32 %0, %1, %2" : "=v"(h0) : "v"(sfv[4*a]),   "v"(sfv[4*a+1]));
    asm("v_cvt_pk_bf16_f32 %0, %1, %2" : "=v"(h1) : "v"(sfv[4*a+2]), "v"(sfv[4*a+3]));
    float r0 = sfv[4*a]   - asf_(h0 << 16);
    float r1 = sfv[4*a+1] - asf_(h0 & 0xffff0000u);
    float r2 = sfv[4*a+2] - asf_(h1 << 16);
    float r3 = sfv[4*a+3] - asf_(h1 & 0xffff0000u);
    unsigned l0, l1;
    asm("v_cvt_pk_bf16_f32 %0, %1, %2" : "=v"(l0) : "v"(r0), "v"(r1));
    asm("v_cvt_pk_bf16_f32 %0, %1, %2" : "=v"(l1) : "v"(r2), "v"(r3));
    ph[a][0]=h0; ph[a][1]=h1; pl[a][0]=l0; pl[a][1]=l1;
  }
}

// ---------------- MFMA flash attention, phase 1: SINGLE-WAVE blocks, no barriers ----
// grid 2176 = b(2) x 1088: band rt 0..127 (32 q-rows), chunks of 256 cols (8 tiles of 32).
// One wave per block; waves on a CU run phase-staggered and independent.
// Swapped MFMA 32x32x16: S^T = K.Q^T, out^T = V^T.P^T. hi/lo bf16 split. P in registers.
__global__ __launch_bounds__(64) void attn_mfma(
    const unsigned short* __restrict__ qhg, const unsigned short* __restrict__ qlg,
    const unsigned short* __restrict__ khg, const unsigned short* __restrict__ klg,
    const unsigned short* __restrict__ vhg, const unsigned short* __restrict__ vlg,
    float* __restrict__ part)
{
  int bid = 2175 - (int)blockIdx.x;           // longest blocks first
  int b = 0, id = bid;
  if (id >= 1088){ b = 1; id -= 1088; }
  int pidx = bid;
  int rem = id, k = 0;
  while (rem >= 8*(k+1)){ rem -= 8*(k+1); ++k; }
  int rt    = 8*k + rem/(k+1);                // 32-row band 0..127
  int chunk = rem - (rem/(k+1))*(k+1);

  int C0  = chunk << 8;                       // 256*chunk
  int end = min(C0 + 256, rt*32 + 32);
  int nt  = (end - C0 + 31) >> 5;             // 1..8 tiles of 32 cols

  int l = threadIdx.x;
  int q = l & 31;
  int hi = l >> 5;
  int n_g = rt*32 + q;                        // this lane's q-row

  __shared__ __align__(16) char KH[4096], KL[4096];   // [32 m][64 d], XOR swz
  __shared__ __align__(16) char VH[5120], VL[5120];   // [64 vd][32 m], 80B row stride, swz

  const unsigned short* qhp = qhg + (size_t)b*NPIX*64;
  const unsigned short* qlp = qlg + (size_t)b*NPIX*64;
  const unsigned short* khp = khg + (size_t)b*NPIX*64;
  const unsigned short* klp = klg + (size_t)b*NPIX*64;
  const unsigned short* vhp = vhg + (size_t)b*CHN*NPIX;
  const unsigned short* vlp = vlg + (size_t)b*CHN*NPIX;

  short8 qhf[4], qlf[4];
  #pragma unroll
  for (int kc=0; kc<4; ++kc){
    qhf[kc] = *(const short8*)(qhp + (size_t)n_g*64 + kc*16 + hi*8);
    qlf[kc] = *(const short8*)(qlp + (size_t)n_g*64 + kc*16 + hi*8);
  }

  // staging slots: K 256 (32 rows x 8 chunks), V 256 (64 rows x 4 chunks); 4/thread each
  int kRow[4], kCc8[4], kOff[4], vRow[4], vCc8[4], vOff[4];
  #pragma unroll
  for (int p=0; p<4; ++p){
    int slot = l + (p<<6);
    int kr = slot >> 3, kc = slot & 7;
    kRow[p] = kr; kCc8[p] = kc*8;
    kOff[p] = kr*128 + ((kc ^ (kr & 7)) << 4);
    int vr = slot >> 2, vc = slot & 3;
    vRow[p] = vr; vCc8[p] = vc*8;
    vOff[p] = vr*80 + ((vc ^ (vr & 3)) << 4);
  }
  ushort8 rkh[4], rkl[4], rvh[4], rvl[4];
  auto issue = [&](int m0){
    #pragma unroll
    for (int p=0; p<4; ++p){
      rkh[p] = *(const ushort8*)(khp + (size_t)(m0+kRow[p])*64 + kCc8[p]);
      rkl[p] = *(const ushort8*)(klp + (size_t)(m0+kRow[p])*64 + kCc8[p]);
      rvh[p] = *(const ushort8*)(vhp + (size_t)vRow[p]*NPIX + m0 + vCc8[p]);
      rvl[p] = *(const ushort8*)(vlp + (size_t)vRow[p]*NPIX + m0 + vCc8[p]);
    }
  };

  f32x16 oacc0, oacc1;
  #pragma unroll
  for (int i=0; i<16; ++i){ oacc0[i]=0.f; oacc1[i]=0.f; }
  float m_run = -1e30f, l_run = 0.f;

  issue(C0);
  for (int ti=0; ti<nt; ++ti){
    int m0 = C0 + (ti<<5);
    // stage (same-wave DS ordering; compiler inserts vmcnt/lgkmcnt waits)
    #pragma unroll
    for (int p=0; p<4; ++p){
      *(ushort8*)(KH + kOff[p]) = rkh[p];
      *(ushort8*)(KL + kOff[p]) = rkl[p];
      *(ushort8*)(VH + vOff[p]) = rvh[p];
      *(ushort8*)(VL + vOff[p]) = rvl[p];
    }
    if (ti+1 < nt) issue(m0 + 32);   // next tile's loads fly under compute

    // ---- S^T = K . Q^T  (12 MFMAs) ----
    f32x16 sf0;
    #pragma unroll
    for (int i=0; i<16; ++i) sf0[i]=0.f;
    __builtin_amdgcn_s_setprio(1);
    #pragma unroll
    for (int kc=0; kc<4; ++kc){
      int off0 = q*128 + (((2*kc + hi) ^ (q & 7)) << 4);
      short8 ah0 = *(const short8*)(KH + off0);
      short8 al0 = *(const short8*)(KL + off0);
      sf0 = __builtin_amdgcn_mfma_f32_32x32x16_bf16(ah0, qhf[kc], sf0, 0,0,0);
      sf0 = __builtin_amdgcn_mfma_f32_32x32x16_bf16(al0, qhf[kc], sf0, 0,0,0);
      sf0 = __builtin_amdgcn_mfma_f32_32x32x16_bf16(ah0, qlf[kc], sf0, 0,0,0);
    }
    __builtin_amdgcn_s_setprio(0);

    // ---- online softmax in exp2 domain (state duplicated on lane^32) ----
    float mx = -1e30f;
    #pragma unroll
    for (int r=0; r<16; ++r){
      int mg0 = m0 + (r&3) + 8*(r>>2) + 4*hi;
      float s0 = (mg0 <= n_g) ? sf0[r] : -1e30f;
      sf0[r] = s0;
      mx = fmaxf(mx, s0);
    }
    mx = fmaxf(mx, __shfl_xor(mx, 32));
    float m_new = fmaxf(m_run, mx);
    float alpha = exp2f(m_run - m_new);
    float ps = 0.f;
    #pragma unroll
    for (int r=0; r<16; ++r){
      float e0 = exp2f(sf0[r] - m_new);
      sf0[r] = e0;
      ps += e0;
    }
    ps += __shfl_xor(ps, 32);
    l_run = l_run*alpha + ps;
    m_run = m_new;

    // ---- P -> bf16 hi/lo quads, in registers ----
    unsigned ph0[4][2], pl0[4][2];
    pack_sf(sf0, ph0, pl0);

    #pragma unroll
    for (int i=0; i<16; ++i){ oacc0[i] *= alpha; oacc1[i] *= alpha; }

    // ---- out^T += V^T . P^T ; P B-frag via lane^32 exchange (12 MFMAs) ----
#define PV_KC(KC) { \
    const int kk = (KC); \
    unsigned oh0 = hi ? ph0[2*kk+1][0] : ph0[2*kk][0]; \
    unsigned oh1 = hi ? ph0[2*kk+1][1] : ph0[2*kk][1]; \
    unsigned sh0 = hi ? ph0[2*kk][0]   : ph0[2*kk+1][0]; \
    unsigned sh1 = hi ? ph0[2*kk][1]   : ph0[2*kk+1][1]; \
    unsigned rh0 = __shfl_xor(sh0, 32); \
    unsigned rh1 = __shfl_xor(sh1, 32); \
    unsigned ol0 = hi ? pl0[2*kk+1][0] : pl0[2*kk][0]; \
    unsigned ol1 = hi ? pl0[2*kk+1][1] : pl0[2*kk][1]; \
    unsigned sl0 = hi ? pl0[2*kk][0]   : pl0[2*kk+1][0]; \
    unsigned sl1 = hi ? pl0[2*kk][1]   : pl0[2*kk+1][1]; \
    unsigned rl0 = __shfl_xor(sl0, 32); \
    unsigned rl1 = __shfl_xor(sl1, 32); \
    union { uint4v u; short8 s; } fh, fl; \
    fh.u[0] = hi ? rh0 : oh0; fh.u[1] = hi ? rh1 : oh1; \
    fh.u[2] = hi ? oh0 : rh0; fh.u[3] = hi ? oh1 : rh1; \
    fl.u[0] = hi ? rl0 : ol0; fl.u[1] = hi ? rl1 : ol1; \
    fl.u[2] = hi ? ol0 : rl0; fl.u[3] = hi ? ol1 : rl1; \
    int vch = ((2*kk + hi) ^ (q & 3)) << 4; \
    short8 xvh0 = *(const short8*)(VH + q*80 + vch); \
    short8 xvl0 = *(const short8*)(VL + q*80 + vch); \
    int vch1 = ((2*kk + hi) ^ (q & 3)) << 4; \
    short8 xvh1 = *(const short8*)(VH + 2560 + q*80 + vch1); \
    short8 xvl1 = *(const short8*)(VL + 2560 + q*80 + vch1); \
    __builtin_amdgcn_s_setprio(1); \
    oacc0 = __builtin_amdgcn_mfma_f32_32x32x16_bf16(xvh0, fh.s, oacc0, 0,0,0); \
    oacc1 = __builtin_amdgcn_mfma_f32_32x32x16_bf16(xvh1, fh.s, oacc1, 0,0,0); \
    oacc0 = __builtin_amdgcn_mfma_f32_32x32x16_bf16(xvl0, fh.s, oacc0, 0,0,0); \
    oacc1 = __builtin_amdgcn_mfma_f32_32x32x16_bf16(xvl1, fh.s, oacc1, 0,0,0); \
    oacc0 = __builtin_amdgcn_mfma_f32_32x32x16_bf16(xvh0, fl.s, oacc0, 0,0,0); \
    oacc1 = __builtin_amdgcn_mfma_f32_32x32x16_bf16(xvh1, fl.s, oacc1, 0,0,0); \
    __builtin_amdgcn_s_setprio(0); \
  }
    PV_KC(0)
    PV_KC(1)
#undef PV_KC
  }

  // ---- write partials: acc [32 rows][64 vd], then m,l [32 rows][2] ----
  float* pacc = part + (size_t)pidx * 2112;
  #pragma unroll
  for (int vf=0; vf<2; ++vf){
    #pragma unroll
    for (int qd=0; qd<4; ++qd){
      int vd = 32*vf + 8*qd + 4*hi;
      f32x4 vv;
      vv.x = vf ? oacc1[4*qd]   : oacc0[4*qd];
      vv.y = vf ? oacc1[4*qd+1] : oacc0[4*qd+1];
      vv.z = vf ? oacc1[4*qd+2] : oacc0[4*qd+2];
      vv.w = vf ? oacc1[4*qd+3] : oacc0[4*qd+3];
      *(f32x4*)(pacc + (size_t)q*64 + vd) = vv;
    }
  }
  if (hi == 0){
    pacc[2048 + q*2]     = m_run;
    pacc[2048 + q*2 + 1] = l_run;
  }
}

// ---------------- attention phase 2: combine partials + emit BN partial sums ----
__global__ __launch_bounds__(256) void attn_combine(const float* __restrict__ part,
                                                    float* __restrict__ out1,
                                                    float* __restrict__ psum,
                                                    float* __restrict__ psq){
  int bid = blockIdx.x;               // b*128 + rt (32-row band)
  int b = bid >> 7, rt = bid & 127;
  int g = rt >> 3;
  int nch = g + 1;                    // <= 16
  int base = b*1088 + 4*g*(g+1) + (rt & 7)*(g+1);

  int t = threadIdx.x;
  int nl = t & 31, vq = t >> 5;       // 32 rows x 8 vd-octets

  float M = -1e30f;
  #pragma unroll
  for (int c=0; c<16; ++c)
    if (c < nch) M = fmaxf(M, part[(size_t)(base+c)*2112 + 2048 + nl*2]);

  float L = 0.f;
  float val[8];
  #pragma unroll
  for (int jj=0; jj<8; ++jj) val[jj] = 0.f;
  #pragma unroll
  for (int c=0; c<16; ++c){
    if (c < nch){
      const float* pa = part + (size_t)(base+c)*2112;
      float wgt = exp2f(pa[2048 + nl*2] - M);
      L += pa[2048 + nl*2 + 1] * wgt;
      #pragma unroll
      for (int jj=0; jj<8; ++jj) val[jj] += wgt * pa[nl*64 + vq*8 + jj];
    }
  }
  float invL = 1.f / L;
  float s[8], q[8];
  #pragma unroll
  for (int jj=0; jj<8; ++jj){
    float v = val[jj]*invL;
    out1[((size_t)b*CHN + vq*8 + jj)*NPIX + rt*32 + nl] = v;
    s[jj] = v; q[jj] = v*v;
  }
  #pragma unroll
  for (int o2=1; o2<32; o2<<=1){
    #pragma unroll
    for (int jj=0; jj<8; ++jj){
      s[jj] += __shfl_xor(s[jj], o2);
      q[jj] += __shfl_xor(q[jj], o2);
    }
  }
  if (nl == 0){
    #pragma unroll
    for (int jj=0; jj<8; ++jj){
      int c = vq*8 + jj;
      psum[c*256 + bid] = s[jj];
      psq [c*256 + bid] = q[jj];
    }
  }
}

// ---------------- final 1x1 conv ----------------
__global__ __launch_bounds__(256) void final_kernel(const float* __restrict__ h,
                                                    const float* __restrict__ ow,
                                                    const float* __restrict__ ob,
                                                    float* __restrict__ out){
  int idx = blockIdx.x*256 + threadIdx.x;     // 819200
  int b  = idx / 409600;
  int r  = idx - b*409600;
  int oc = r >> 12;
  int n  = r & (NPIX-1);
  const float* hp = h + (size_t)b*CHN*NPIX + n;
  const float* wp = ow + oc*64;
  float acc = ob[oc];
  #pragma unroll
  for (int v=0; v<64; ++v) acc += wp[v]*hp[(size_t)v*NPIX];
  out[idx] = acc;
}

extern "C" void kernel_launch(void* const* d_in, const int* in_sizes, int n_in,
                              void* d_out, int out_size, void* d_ws, size_t ws_size,
                              hipStream_t stream){
  const float* x     = (const float*)d_in[0];
  const float* convw = (const float*)d_in[1];
  const float* convb = (const float*)d_in[2];
  const float* bn0g  = (const float*)d_in[3];
  const float* bn0b  = (const float*)d_in[4];
  const float* qw    = (const float*)d_in[5];
  const float* qbias = (const float*)d_in[6];
  const float* fkw   = (const float*)d_in[7];
  const float* fkb   = (const float*)d_in[8];
  const float* ckw   = (const float*)d_in[9];
  const float* ckb   = (const float*)d_in[10];
  const float* fvw   = (const float*)d_in[11];
  const float* fvb   = (const float*)d_in[12];
  const float* cvw   = (const float*)d_in[13];
  const float* cvb   = (const float*)d_in[14];
  const float* bng   = (const float*)d_in[15];
  const float* bnb   = (const float*)d_in[16];
  const float* ow    = (const float*)d_in[17];
  const float* ob    = (const float*)d_in[18];

  const size_t TEN = (size_t)2*CHN*NPIX;   // 524288 elements
  const size_t BFU = TEN/2;
  float* ws   = (float*)d_ws;
  float* pos  = ws;                 // 131072
  float* h    = pos + 32*NPIX;      // 524288
  float* k0   = h  + TEN;
  float* k1   = k0 + TEN;
  float* v0   = k1 + TEN;
  float* v1   = v0 + TEN;
  float* stats = v1 + TEN;          // 128
  float* psum = stats + 128;        // 64*256
  float* psq  = psum + 64*256;      // 64*256
  float* wt   = psq + 64*256;       // 381632
  float* bfb  = wt + 381632;
  unsigned short* qh  = (unsigned short*)(bfb);
  unsigned short* ql  = (unsigned short*)(bfb + BFU);
  unsigned short* kh0 = (unsigned short*)(bfb + 2*BFU);
  unsigned short* kh1 = (unsigned short*)(bfb + 3*BFU);
  unsigned short* kl0 = (unsigned short*)(bfb + 4*BFU);
  unsigned short* kl1 = (unsigned short*)(bfb + 5*BFU);
  unsigned short* vh0 = (unsigned short*)(bfb + 6*BFU);
  unsigned short* vh1 = (unsigned short*)(bfb + 7*BFU);
  unsigned short* vl0 = (unsigned short*)(bfb + 8*BFU);
  unsigned short* vl1 = (unsigned short*)(bfb + 9*BFU);
  float* part = bfb + 10*BFU;       // 2176 * 2112 floats

  hipMemsetAsync(k0, 0, TEN*sizeof(float), stream);
  hipMemsetAsync(v0, 0, TEN*sizeof(float), stream);
  hipMemsetAsync(kh0, 0, TEN*2, stream);
  hipMemsetAsync(kl0, 0, TEN*2, stream);
  hipMemsetAsync(vh0, 0, TEN*2, stream);
  hipMemsetAsync(vl0, 0, TEN*2, stream);

  pos_kernel<<<512,256,0,stream>>>(pos);
  wtr_kernel<<<1491,256,0,stream>>>(qw, fkw, ckw, fvw, cvw, convw, wt);
  conv_in_kernel<<<2048,256,0,stream>>>(x, wt + 376832, convb, h);
  bn_stats_kernel<<<64,1024,0,stream>>>(h, stats);
  bn_apply_kernel<<<512,256,0,stream>>>(h, stats, bn0g, bn0b, h);

  float* kfp[2] = {k0,k1};
  float* vfp[2] = {v0,v1};
  unsigned short* khb[2] = {kh0,kh1};
  unsigned short* klb[2] = {kl0,kl1};
  unsigned short* vhb[2] = {vh0,vh1};
  unsigned short* vlb[2] = {vl0,vl1};
  for (int l=0; l<8; ++l){
    float* kold = kfp[l&1]; float* knew = kfp[(l+1)&1];
    float* vold = vfp[l&1]; float* vnew = vfp[(l+1)&1];
    cv1_kernel<<<1536,256,0,stream>>>(h, pos, kold, vold,
        wt + l*6144,
        wt + 49152 + l*10240,
        wt + 49152 + 81920 + l*10240,
        wt + 49152 + 2*81920 + l*10240,
        wt + 49152 + 3*81920 + l*10240,
        qbias + l*64, fkb + l*64, ckb + l*64, fvb + l*64, cvb + l*64,
        qh, ql,
        knew, khb[(l+1)&1], klb[(l+1)&1],
        vnew, vhb[(l+1)&1], vlb[(l+1)&1]);
    attn_mfma<<<2176,64,0,stream>>>(qh, ql, khb[l&1], klb[l&1], vhb[l&1], vlb[l&1], part);
    attn_combine<<<256,256,0,stream>>>(part, h, psum, psq);
    bn_apply2_kernel<<<512,256,0,stream>>>(h, psum, psq, bng + l*64, bnb + l*64);
  }
  final_kernel<<<3200,256,0,stream>>>(h, ow, ob, (float*)d_out);
}

// Round 13
// 795.521 us; speedup vs baseline: 1.1145x; 1.1145x over previous
//
#include <hip/hip_runtime.h>

#define NPIX 4096
#define CHN  64

typedef __attribute__((ext_vector_type(8))) short short8;
typedef __attribute__((ext_vector_type(8))) unsigned short ushort8;
typedef __attribute__((ext_vector_type(4))) unsigned short ushort4v;
typedef __attribute__((ext_vector_type(4))) float f32x4;

__device__ __forceinline__ float lrelu_(float x){ return x >= 0.f ? x : 0.01f*x; }

__device__ __forceinline__ unsigned short f2bf(float x){
  union { float f; unsigned u; } v; v.f = x;
  unsigned r = v.u + 0x7FFF + ((v.u >> 16) & 1);
  return (unsigned short)(r >> 16);
}
__device__ __forceinline__ float bf2f(unsigned short h){
  union { unsigned u; float f; } v; v.u = ((unsigned)h) << 16;
  return v.f;
}

// ---------------- positional embedding table [32][4096] ----------------
__global__ void pos_kernel(float* __restrict__ pos){
  int idx = blockIdx.x*256 + threadIdx.x;       // 32*4096 = 131072
  int c = idx >> 12;
  int n = idx & (NPIX-1);
  int bcoord = (c < 16) ? (n >> 6) : (n & 63);
  int a = (c < 16) ? c : (c - 16);
  int flat = a*64 + bcoord;                     // index into pe flat [64*16]
  int p = flat >> 4;
  int j = flat & 15;
  float val = 0.f;
  if (p != 0){
    float ex = (float)(j & ~1) * (1.f/16.f);
    float w = powf(10000.f, -ex);
    float ang = (float)p * w;
    val = (j & 1) ? cosf(ang) : sinf(ang);
  }
  pos[idx] = val;
}

// ---------------- weight transpose ----------------
// wt: q [l][i][o] 49152 | fk/ck/fv/cv [l][i][o] 81920 each | conv [tap75][o64] 4800
__global__ void wtr_kernel(const float* __restrict__ qw, const float* __restrict__ fkw,
                           const float* __restrict__ ckw, const float* __restrict__ fvw,
                           const float* __restrict__ cvw, const float* __restrict__ convw,
                           float* __restrict__ wt){
  int idx = blockIdx.x*256 + threadIdx.x;
  if (idx >= 381632) return;
  if (idx < 49152){
    int l = idx / 6144, r = idx % 6144, i = r >> 6, o = r & 63;
    wt[idx] = qw[(l*64 + o)*96 + i];
  } else if (idx < 376832){
    int e = idx - 49152;
    int mat = e / 81920, r = e % 81920;
    int l = r / 10240, rr = r % 10240, i = rr >> 6, o = rr & 63;
    const float* src = (mat==0) ? fkw : (mat==1) ? ckw : (mat==2) ? fvw : cvw;
    wt[idx] = src[(l*64 + o)*160 + i];
  } else {
    int e = idx - 376832;          // [tap][o], tap = ci*25 + (ky*5+kx)
    int o = e & 63, tap = e >> 6;
    int ci = tap / 25, r = tap % 25;
    wt[idx] = convw[(o*3 + ci)*25 + r];
  }
}

// ---------------- masked causal 5x5 conv (input layer) ----------------
__global__ __launch_bounds__(256) void conv_in_kernel(const float* __restrict__ x,
                                                      const float* __restrict__ cwt,
                                                      const float* __restrict__ cb,
                                                      float* __restrict__ out){
  int t = threadIdx.x;
  int o = t & 63;
  int sub = t >> 6;
  int bid = blockIdx.x;
  int b = bid >> 10;
  int n = ((bid & 1023) << 2) + sub;
  int y = n >> 6, xx = n & 63;
  float acc = cb[o];
  #pragma unroll
  for (int ci=0; ci<3; ++ci){
    const float* xp = x + ((b*3+ci)<<12);
    #pragma unroll
    for (int ky=0; ky<3; ++ky){
      int yy = y + ky - 2;
      if (yy < 0) continue;
      int nk = (ky==2) ? 2 : 5;
      #pragma unroll
      for (int kx=0; kx<5; ++kx){
        if (kx >= nk) break;
        int xc = xx + kx - 2;
        if (xc < 0 || xc > 63) continue;
        acc += xp[(yy<<6) + xc] * cwt[(ci*25 + ky*5 + kx)*64 + o];
      }
    }
  }
  out[(b*CHN+o)*NPIX + n] = acc;
}

// ---------------- batch-norm stats (conv path only) ----------------
__global__ __launch_bounds__(1024) void bn_stats_kernel(const float* __restrict__ xin,
                                                        float* __restrict__ stats){
  int c = blockIdx.x;
  int t = threadIdx.x;
  float s = 0.f, ss = 0.f;
  #pragma unroll
  for (int it=0; it<8; ++it){
    int idx = t + it*1024;
    float v = xin[(((idx>>12))*CHN + c)*NPIX + (idx & (NPIX-1))];
    s += v; ss += v*v;
  }
  #pragma unroll
  for (int o=1; o<64; o<<=1){ s += __shfl_xor(s,o); ss += __shfl_xor(ss,o); }
  __shared__ float ps[16], pq[16];
  if ((t & 63) == 0){ ps[t>>6] = s; pq[t>>6] = ss; }
  __syncthreads();
  if (t == 0){
    float S=0.f, Q=0.f;
    #pragma unroll
    for (int i=0;i<16;++i){ S += ps[i]; Q += pq[i]; }
    float mu = S*(1.f/8192.f);
    float var = Q*(1.f/8192.f) - mu*mu;
    var = fmaxf(var, 0.f);
    stats[c*2]   = mu;
    stats[c*2+1] = rsqrtf(var + 1e-5f);
  }
}

// ---------------- BN apply + LeakyReLU (conv path) ----------------
__global__ void bn_apply_kernel(const float* __restrict__ xin, const float* __restrict__ stats,
                                const float* __restrict__ g, const float* __restrict__ bb,
                                float* __restrict__ hout){
  int idx = blockIdx.x*256 + threadIdx.x;
  int e = idx << 2;
  int c = (e >> 12) & 63;
  float mu = stats[c*2], rstd = stats[c*2+1];
  float gain = g[c]*rstd;
  float beta = bb[c] - gain*mu;
  float4 v = *(const float4*)(xin + e);
  float4 r;
  r.x = lrelu_(gain*v.x + beta);
  r.y = lrelu_(gain*v.y + beta);
  r.z = lrelu_(gain*v.z + beta);
  r.w = lrelu_(gain*v.w + beta);
  *(float4*)(hout + e) = r;
}

// ---------------- BN apply + LeakyReLU from per-seg partials (in-place) ---
__global__ __launch_bounds__(256) void bn_apply2_kernel(float* __restrict__ hbuf,
                                                        const float* __restrict__ psum,
                                                        const float* __restrict__ psq,
                                                        const float* __restrict__ g,
                                                        const float* __restrict__ bb){
  int bid = blockIdx.x;
  int ebase = bid << 10;
  int c = (ebase >> 12) & 63;
  int t = threadIdx.x;
  float s = psum[c*256 + t];
  float q = psq[c*256 + t];
  #pragma unroll
  for (int o=1; o<64; o<<=1){ s += __shfl_xor(s,o); q += __shfl_xor(q,o); }
  __shared__ float as[4], aq[4];
  if ((t & 63) == 0){ as[t>>6] = s; aq[t>>6] = q; }
  __syncthreads();
  float S = as[0]+as[1]+as[2]+as[3];
  float Q = aq[0]+aq[1]+aq[2]+aq[3];
  float mu = S*(1.f/8192.f);
  float var = fmaxf(Q*(1.f/8192.f) - mu*mu, 0.f);
  float rstd = rsqrtf(var + 1e-5f);
  float gain = g[c]*rstd;
  float beta = bb[c] - gain*mu;
  float4 v = *(const float4*)(hbuf + ebase + t*4);
  float4 r;
  r.x = lrelu_(gain*v.x + beta);
  r.y = lrelu_(gain*v.y + beta);
  r.z = lrelu_(gain*v.z + beta);
  r.w = lrelu_(gain*v.w + beta);
  *(float4*)(hbuf + ebase + t*4) = r;
}

// ---------------- five 1x1 convs, section-split ----------------
// grid 1536 = sec(3) x b(2) x tile(256 of 16 px); block 256 = 4 waves x 4 px.
__global__ __launch_bounds__(256) void cv1_kernel(
    const float* __restrict__ hbuf, const float* __restrict__ pos,
    const float* __restrict__ kold, const float* __restrict__ vold,
    const float* __restrict__ qwt,
    const float* __restrict__ fkwt, const float* __restrict__ ckwt,
    const float* __restrict__ fvwt, const float* __restrict__ cvwt,
    const float* __restrict__ qbi,  const float* __restrict__ fkb,
    const float* __restrict__ ckb,  const float* __restrict__ fvb,
    const float* __restrict__ cvb,
    unsigned short* __restrict__ qh, unsigned short* __restrict__ ql,
    float* __restrict__ knew, unsigned short* __restrict__ khn, unsigned short* __restrict__ kln,
    float* __restrict__ vnew, unsigned short* __restrict__ vhTn, unsigned short* __restrict__ vlTn)
{
  int t = threadIdx.x;
  int o  = t & 63;
  int wv = t >> 6;                      // 0..3
  int sec  = blockIdx.x >> 9;           // 0,1,2
  int bid  = blockIdx.x & 511;
  int b    = bid >> 8;
  int tile = bid & 255;
  int n0 = tile*16 + wv*4;

  const float* hb = hbuf + b*CHN*NPIX + n0;
  const float* pb = pos + n0;

  auto load4 = [&](const float* p, float* dst){
    float4 a = *(const float4*)p;
    dst[0]=a.x; dst[1]=a.y; dst[2]=a.z; dst[3]=a.w;
  };

  float x[4];
  long obase = (long)(b*CHN+o)*NPIX + n0;
  size_t nbase = ((size_t)b*NPIX + n0)*64 + o;

  if (sec == 0){
    float aq[4];
    float bias = qbi[o];
    #pragma unroll
    for (int j=0;j<4;++j) aq[j]=bias;
    #pragma unroll 4
    for (int i=0;i<64;++i){
      load4(hb + i*NPIX, x);
      float w = qwt[i*64 + o];
      #pragma unroll
      for (int j=0;j<4;++j) aq[j] += w*x[j];
    }
    #pragma unroll 4
    for (int i=0;i<32;++i){
      load4(pb + i*NPIX, x);
      float w = qwt[(64+i)*64 + o];
      #pragma unroll
      for (int j=0;j<4;++j) aq[j] += w*x[j];
    }
    const float QS = 0.125f;            // expf-domain softmax (R6 attn)
    #pragma unroll
    for (int j=0;j<4;++j){
      float v = lrelu_(aq[j]) * QS;
      unsigned short hb16 = f2bf(v);
      qh[nbase + (size_t)j*64] = hb16;
      ql[nbase + (size_t)j*64] = f2bf(v - bf2f(hb16));
    }
  } else if (sec == 1){
    const float* kb = kold + b*CHN*NPIX + n0;
    float af[4], ac[4];
    float bf = fkb[o], bc = ckb[o];
    #pragma unroll
    for (int j=0;j<4;++j){ af[j]=bf; ac[j]=bc; }
    #pragma unroll 4
    for (int i=0;i<64;++i){
      load4(hb + i*NPIX, x);
      float wf = fkwt[i*64+o], wc = ckwt[i*64+o];
      #pragma unroll
      for (int j=0;j<4;++j){ af[j] += wf*x[j]; ac[j] += wc*x[j]; }
    }
    #pragma unroll 4
    for (int i=0;i<32;++i){
      load4(pb + i*NPIX, x);
      float wf = fkwt[(64+i)*64+o], wc = ckwt[(64+i)*64+o];
      #pragma unroll
      for (int j=0;j<4;++j){ af[j] += wf*x[j]; ac[j] += wc*x[j]; }
    }
    #pragma unroll 4
    for (int i=0;i<64;++i){
      load4(kb + i*NPIX, x);
      float wf = fkwt[(96+i)*64+o], wc = ckwt[(96+i)*64+o];
      #pragma unroll
      for (int j=0;j<4;++j){ af[j] += wf*x[j]; ac[j] += wc*x[j]; }
    }
    float kv[4];
    load4(kb + o*NPIX, kv);
    #pragma unroll
    for (int j=0;j<4;++j){
      float fk = 1.f/(1.f+__expf(-af[j]));
      float kn = fk*kv[j] + lrelu_(ac[j]);
      knew[obase+j] = kn;
      unsigned short hb16 = f2bf(kn);
      khn[nbase + (size_t)j*64] = hb16;
      kln[nbase + (size_t)j*64] = f2bf(kn - bf2f(hb16));
    }
  } else {
    const float* vb = vold + b*CHN*NPIX + n0;
    float af[4], ac[4];
    float bf = fvb[o], bc = cvb[o];
    #pragma unroll
    for (int j=0;j<4;++j){ af[j]=bf; ac[j]=bc; }
    #pragma unroll 4
    for (int i=0;i<64;++i){
      load4(hb + i*NPIX, x);
      float wf = fvwt[i*64+o], wc = cvwt[i*64+o];
      #pragma unroll
      for (int j=0;j<4;++j){ af[j] += wf*x[j]; ac[j] += wc*x[j]; }
    }
    #pragma unroll 4
    for (int i=0;i<32;++i){
      load4(pb + i*NPIX, x);
      float wf = fvwt[(64+i)*64+o], wc = cvwt[(64+i)*64+o];
      #pragma unroll
      for (int j=0;j<4;++j){ af[j] += wf*x[j]; ac[j] += wc*x[j]; }
    }
    #pragma unroll 4
    for (int i=0;i<64;++i){
      load4(vb + i*NPIX, x);
      float wf = fvwt[(96+i)*64+o], wc = cvwt[(96+i)*64+o];
      #pragma unroll
      for (int j=0;j<4;++j){ af[j] += wf*x[j]; ac[j] += wc*x[j]; }
    }
    float vv[4];
    load4(vb + o*NPIX, vv);
    ushort4v vph, vpl;
    #pragma unroll
    for (int j=0;j<4;++j){
      float fv = 1.f/(1.f+__expf(-af[j]));
      float vn = fv*vv[j] + lrelu_(ac[j]);
      vnew[obase+j] = vn;
      unsigned short hb16 = f2bf(vn);
      vph[j] = hb16;
      vpl[j] = f2bf(vn - bf2f(hb16));
    }
    *(ushort4v*)(vhTn + ((size_t)(b*CHN+o))*NPIX + n0) = vph;
    *(ushort4v*)(vlTn + ((size_t)(b*CHN+o))*NPIX + n0) = vpl;
  }
}

// ---------------- MFMA flash attention (R6 config: 16x16x32, 640 blocks) ----
// grid 640: b(2) x band decomposition (rt 0..127 [32 rows], chunks of 1024 cols).
// block 128 = 2 waves x 16 q-rows. Swapped MFMA: S^T = K.Q^T, out^T = V^T.P^T.
// hi/lo bf16 split (3 MFMAs per product); T14 reg-prefetch; expf-domain softmax.
__global__ __launch_bounds__(128) void attn_mfma(
    const unsigned short* __restrict__ qhg, const unsigned short* __restrict__ qlg,
    const unsigned short* __restrict__ khg, const unsigned short* __restrict__ klg,
    const unsigned short* __restrict__ vhg, const unsigned short* __restrict__ vlg,
    float* __restrict__ part)
{
  int bid = 639 - (int)blockIdx.x;           // longest bands dispatched first
  int b = 0, id = bid;
  if (id >= 320){ b = 1; id -= 320; }
  int pidx = bid;
  int rem = id, k = 0;
  while (rem >= 32*(k+1)){ rem -= 32*(k+1); ++k; }
  int rt    = 32*k + rem/(k+1);
  int chunk = rem - (rem/(k+1))*(k+1);

  int C0  = chunk << 10;                      // 1024*chunk
  int end = min(C0 + 1024, rt*32 + 32);
  int nt  = (end - C0 + 63) >> 6;

  int t = threadIdx.x;
  int w = t >> 6;
  int l = t & 63;
  int r = l & 15;
  int g = l >> 4;
  int n_g = rt*32 + w*16 + r;                 // this lane's q-row

  __shared__ __align__(16) char KH[8192], KL[8192];  // [64 m][64 d] bf16, chunk-XOR swizzle
  __shared__ __align__(16) char VH[8192], VL[8192];  // [64 vd][64 m] bf16, swizzled
  __shared__ __align__(16) char PH[2][2048], PL[2][2048]; // per-wave [16 n][64 m]

  const unsigned short* qhp = qhg + (size_t)b*NPIX*64;
  const unsigned short* qlp = qlg + (size_t)b*NPIX*64;
  const unsigned short* khp = khg + (size_t)b*NPIX*64;
  const unsigned short* klp = klg + (size_t)b*NPIX*64;
  const unsigned short* vhp = vhg + (size_t)b*CHN*NPIX;
  const unsigned short* vlp = vlg + (size_t)b*CHN*NPIX;

  short8 qh0 = *(const short8*)(qhp + (size_t)n_g*64 + 8*g);
  short8 qh1 = *(const short8*)(qhp + (size_t)n_g*64 + 8*g + 32);
  short8 ql0 = *(const short8*)(qlp + (size_t)n_g*64 + 8*g);
  short8 ql1 = *(const short8*)(qlp + (size_t)n_g*64 + 8*g + 32);

  // per-thread staging slots (computed once)
  int srow[4], scc8[4], soff[4];
  #pragma unroll
  for (int p=0; p<4; ++p){
    int slot = t + (p<<7);
    int row = slot >> 3, cc = slot & 7;
    srow[p] = row; scc8[p] = cc*8;
    soff[p] = row*128 + ((cc ^ (row & 7)) << 4);
  }

  ushort8 rkh[4], rkl[4], rvh[4], rvl[4];
  auto issue = [&](int m0){
    #pragma unroll
    for (int p=0; p<4; ++p){
      rkh[p] = *(const ushort8*)(khp + (size_t)(m0+srow[p])*64 + scc8[p]);
      rkl[p] = *(const ushort8*)(klp + (size_t)(m0+srow[p])*64 + scc8[p]);
      rvh[p] = *(const ushort8*)(vhp + (size_t)srow[p]*NPIX + m0 + scc8[p]);
      rvl[p] = *(const ushort8*)(vlp + (size_t)srow[p]*NPIX + m0 + scc8[p]);
    }
  };

  f32x4 zero4 = {0.f,0.f,0.f,0.f};
  f32x4 oacc[4];
  #pragma unroll
  for (int vf=0; vf<4; ++vf) oacc[vf] = zero4;
  float m_run = -1e30f, l_run = 0.f;

  int nmax_w = rt*32 + w*16 + 15;

  issue(C0);
  for (int ti=0; ti<nt; ++ti){
    int m0 = C0 + (ti<<6);
    __syncthreads();                 // previous tile's LDS reads complete
    #pragma unroll
    for (int p=0; p<4; ++p){
      *(ushort8*)(KH + soff[p]) = rkh[p];
      *(ushort8*)(KL + soff[p]) = rkl[p];
      *(ushort8*)(VH + soff[p]) = rvh[p];
      *(ushort8*)(VL + soff[p]) = rvl[p];
    }
    __syncthreads();                 // tile staged
    if (ti+1 < nt) issue(m0 + 64);   // next tile's loads fly under compute

    if (m0 <= nmax_w){
      // ---- S^T = K . Q^T ----
      f32x4 sf[4];
      #pragma unroll
      for (int mf=0; mf<4; ++mf) sf[mf] = zero4;
      #pragma unroll
      for (int kc=0; kc<2; ++kc){
        short8 qfh = kc ? qh1 : qh0;
        short8 qfl = kc ? ql1 : ql0;
        int ch = ((g + 4*kc) ^ (r & 7)) << 4;
        #pragma unroll
        for (int mf=0; mf<4; ++mf){
          int ro = (16*mf + r)*128;
          short8 ah = *(const short8*)(KH + ro + ch);
          short8 al = *(const short8*)(KL + ro + ch);
          sf[mf] = __builtin_amdgcn_mfma_f32_16x16x32_bf16(ah, qfh, sf[mf], 0,0,0);
          sf[mf] = __builtin_amdgcn_mfma_f32_16x16x32_bf16(al, qfh, sf[mf], 0,0,0);
          sf[mf] = __builtin_amdgcn_mfma_f32_16x16x32_bf16(ah, qfl, sf[mf], 0,0,0);
        }
      }
      // ---- online softmax: lane owns row n_g (scale pre-folded into q) ----
      float pv[16];
      float mx = -1e30f;
      #pragma unroll
      for (int mf=0; mf<4; ++mf){
        #pragma unroll
        for (int q2=0; q2<4; ++q2){
          int mg = m0 + 16*mf + 4*g + q2;
          float s = sf[mf][q2];
          s = (mg <= n_g) ? s : -1e30f;
          pv[mf*4+q2] = s;
          mx = fmaxf(mx, s);
        }
      }
      mx = fmaxf(mx, __shfl_xor(mx, 16));
      mx = fmaxf(mx, __shfl_xor(mx, 32));
      float m_new = fmaxf(m_run, mx);
      float alpha = __expf(m_run - m_new);
      float ps = 0.f;
      #pragma unroll
      for (int i=0; i<16; ++i){ pv[i] = __expf(pv[i] - m_new); ps += pv[i]; }
      ps += __shfl_xor(ps, 16);
      ps += __shfl_xor(ps, 32);
      l_run = l_run*alpha + ps;
      m_run = m_new;

      // ---- pack P hi/lo -> per-wave LDS tiles (same-wave, in-order DS) ----
      #pragma unroll
      for (int mf=0; mf<4; ++mf){
        unsigned short h_[4], l_[4];
        #pragma unroll
        for (int q2=0; q2<4; ++q2){
          float xv = pv[mf*4+q2];
          h_[q2] = f2bf(xv);
          l_[q2] = f2bf(xv - bf2f(h_[q2]));
        }
        int addr = r*128 + ((((g>>1) + 2*mf) ^ (r & 7)) << 4) + ((g&1)<<3);
        uint2 wh = make_uint2((unsigned)h_[0] | ((unsigned)h_[1]<<16),
                              (unsigned)h_[2] | ((unsigned)h_[3]<<16));
        uint2 wl = make_uint2((unsigned)l_[0] | ((unsigned)l_[1]<<16),
                              (unsigned)l_[2] | ((unsigned)l_[3]<<16));
        *(uint2*)(PH[w] + addr) = wh;
        *(uint2*)(PL[w] + addr) = wl;
      }
      #pragma unroll
      for (int vf=0; vf<4; ++vf) oacc[vf] *= alpha;

      // ---- out^T += V^T . P^T ----
      #pragma unroll
      for (int kc=0; kc<2; ++kc){
        int ch = ((g + 4*kc) ^ (r & 7)) << 4;
        short8 pfh = *(const short8*)(PH[w] + r*128 + ch);
        short8 pfl = *(const short8*)(PL[w] + r*128 + ch);
        #pragma unroll
        for (int vf=0; vf<4; ++vf){
          int ro = (16*vf + r)*128;
          short8 ah = *(const short8*)(VH + ro + ch);
          short8 al = *(const short8*)(VL + ro + ch);
          oacc[vf] = __builtin_amdgcn_mfma_f32_16x16x32_bf16(ah, pfh, oacc[vf], 0,0,0);
          oacc[vf] = __builtin_amdgcn_mfma_f32_16x16x32_bf16(al, pfh, oacc[vf], 0,0,0);
          oacc[vf] = __builtin_amdgcn_mfma_f32_16x16x32_bf16(ah, pfl, oacc[vf], 0,0,0);
        }
      }
    }
  }

  // ---- write partials: acc [32 n][64 vd], then m,l [32 n][2] ----
  float* pacc = part + (size_t)pidx * 2112;
  int nl = w*16 + r;
  #pragma unroll
  for (int vf=0; vf<4; ++vf)
    *(f32x4*)(pacc + nl*64 + 16*vf + 4*g) = oacc[vf];
  if (g == 0){
    pacc[2048 + nl*2]   = m_run;
    pacc[2048 + nl*2+1] = l_run;
  }
}

// ---------------- attention phase 2: combine partials + emit BN partial sums ----
__global__ __launch_bounds__(256) void attn_combine(const float* __restrict__ part,
                                                    float* __restrict__ out1,
                                                    float* __restrict__ psum,
                                                    float* __restrict__ psq){
  int bid = blockIdx.x;               // b*128 + rt
  int b = bid >> 7, rt = bid & 127;
  int k = rt >> 5;
  int nch = k + 1;                    // <= 4
  int base = b*320 + 16*k*(k+1) + (rt - 32*k)*nch;

  int t = threadIdx.x;
  int nl = t & 31, vq = t >> 5;       // 32 rows x 8 vd-octets

  float M = -1e30f;
  #pragma unroll
  for (int c=0; c<4; ++c)
    if (c < nch) M = fmaxf(M, part[(size_t)(base+c)*2112 + 2048 + nl*2]);

  float L = 0.f;
  float val[8];
  #pragma unroll
  for (int jj=0; jj<8; ++jj) val[jj] = 0.f;
  #pragma unroll
  for (int c=0; c<4; ++c){
    if (c < nch){
      const float* pa = part + (size_t)(base+c)*2112;
      float wgt = __expf(pa[2048 + nl*2] - M);
      L += pa[2048 + nl*2 + 1] * wgt;
      #pragma unroll
      for (int jj=0; jj<8; ++jj) val[jj] += wgt * pa[nl*64 + vq*8 + jj];
    }
  }
  float invL = 1.f / L;
  float s[8], q[8];
  #pragma unroll
  for (int jj=0; jj<8; ++jj){
    float v = val[jj]*invL;
    out1[((size_t)b*CHN + vq*8 + jj)*NPIX + rt*32 + nl] = v;
    s[jj] = v; q[jj] = v*v;
  }
  #pragma unroll
  for (int o2=1; o2<32; o2<<=1){
    #pragma unroll
    for (int jj=0; jj<8; ++jj){
      s[jj] += __shfl_xor(s[jj], o2);
      q[jj] += __shfl_xor(q[jj], o2);
    }
  }
  if (nl == 0){
    #pragma unroll
    for (int jj=0; jj<8; ++jj){
      int c = vq*8 + jj;
      psum[c*256 + bid] = s[jj];
      psq [c*256 + bid] = q[jj];
    }
  }
}

// ---------------- final 1x1 conv ----------------
__global__ __launch_bounds__(256) void final_kernel(const float* __restrict__ h,
                                                    const float* __restrict__ ow,
                                                    const float* __restrict__ ob,
                                                    float* __restrict__ out){
  int idx = blockIdx.x*256 + threadIdx.x;     // 819200
  int b  = idx / 409600;
  int r  = idx - b*409600;
  int oc = r >> 12;
  int n  = r & (NPIX-1);
  const float* hp = h + (size_t)b*CHN*NPIX + n;
  const float* wp = ow + oc*64;
  float acc = ob[oc];
  #pragma unroll
  for (int v=0; v<64; ++v) acc += wp[v]*hp[(size_t)v*NPIX];
  out[idx] = acc;
}

extern "C" void kernel_launch(void* const* d_in, const int* in_sizes, int n_in,
                              void* d_out, int out_size, void* d_ws, size_t ws_size,
                              hipStream_t stream){
  const float* x     = (const float*)d_in[0];
  const float* convw = (const float*)d_in[1];
  const float* convb = (const float*)d_in[2];
  const float* bn0g  = (const float*)d_in[3];
  const float* bn0b  = (const float*)d_in[4];
  const float* qw    = (const float*)d_in[5];
  const float* qbias = (const float*)d_in[6];
  const float* fkw   = (const float*)d_in[7];
  const float* fkb   = (const float*)d_in[8];
  const float* ckw   = (const float*)d_in[9];
  const float* ckb   = (const float*)d_in[10];
  const float* fvw   = (const float*)d_in[11];
  const float* fvb   = (const float*)d_in[12];
  const float* cvw   = (const float*)d_in[13];
  const float* cvb   = (const float*)d_in[14];
  const float* bng   = (const float*)d_in[15];
  const float* bnb   = (const float*)d_in[16];
  const float* ow    = (const float*)d_in[17];
  const float* ob    = (const float*)d_in[18];

  const size_t TEN = (size_t)2*CHN*NPIX;   // 524288 elements
  const size_t BFU = TEN/2;
  float* ws   = (float*)d_ws;
  float* pos  = ws;                 // 131072
  float* h    = pos + 32*NPIX;      // 524288
  float* k0   = h  + TEN;
  float* k1   = k0 + TEN;
  float* v0   = k1 + TEN;
  float* v1   = v0 + TEN;
  float* stats = v1 + TEN;          // 128
  float* psum = stats + 128;        // 64*256
  float* psq  = psum + 64*256;      // 64*256
  float* wt   = psq + 64*256;       // 381632
  float* bfb  = wt + 381632;
  unsigned short* qh  = (unsigned short*)(bfb);
  unsigned short* ql  = (unsigned short*)(bfb + BFU);
  unsigned short* kh0 = (unsigned short*)(bfb + 2*BFU);
  unsigned short* kh1 = (unsigned short*)(bfb + 3*BFU);
  unsigned short* kl0 = (unsigned short*)(bfb + 4*BFU);
  unsigned short* kl1 = (unsigned short*)(bfb + 5*BFU);
  unsigned short* vh0 = (unsigned short*)(bfb + 6*BFU);
  unsigned short* vh1 = (unsigned short*)(bfb + 7*BFU);
  unsigned short* vl0 = (unsigned short*)(bfb + 8*BFU);
  unsigned short* vl1 = (unsigned short*)(bfb + 9*BFU);
  float* part = bfb + 10*BFU;       // 640 * 2112 floats

  hipMemsetAsync(k0, 0, TEN*sizeof(float), stream);
  hipMemsetAsync(v0, 0, TEN*sizeof(float), stream);
  hipMemsetAsync(kh0, 0, TEN*2, stream);
  hipMemsetAsync(kl0, 0, TEN*2, stream);
  hipMemsetAsync(vh0, 0, TEN*2, stream);
  hipMemsetAsync(vl0, 0, TEN*2, stream);

  pos_kernel<<<512,256,0,stream>>>(pos);
  wtr_kernel<<<1491,256,0,stream>>>(qw, fkw, ckw, fvw, cvw, convw, wt);
  conv_in_kernel<<<2048,256,0,stream>>>(x, wt + 376832, convb, h);
  bn_stats_kernel<<<64,1024,0,stream>>>(h, stats);
  bn_apply_kernel<<<512,256,0,stream>>>(h, stats, bn0g, bn0b, h);

  float* kfp[2] = {k0,k1};
  float* vfp[2] = {v0,v1};
  unsigned short* khb[2] = {kh0,kh1};
  unsigned short* klb[2] = {kl0,kl1};
  unsigned short* vhb[2] = {vh0,vh1};
  unsigned short* vlb[2] = {vl0,vl1};
  for (int l=0; l<8; ++l){
    float* kold = kfp[l&1]; float* knew = kfp[(l+1)&1];
    float* vold = vfp[l&1]; float* vnew = vfp[(l+1)&1];
    cv1_kernel<<<1536,256,0,stream>>>(h, pos, kold, vold,
        wt + l*6144,
        wt + 49152 + l*10240,
        wt + 49152 + 81920 + l*10240,
        wt + 49152 + 2*81920 + l*10240,
        wt + 49152 + 3*81920 + l*10240,
        qbias + l*64, fkb + l*64, ckb + l*64, fvb + l*64, cvb + l*64,
        qh, ql,
        knew, khb[(l+1)&1], klb[(l+1)&1],
        vnew, vhb[(l+1)&1], vlb[(l+1)&1]);
    attn_mfma<<<640,128,0,stream>>>(qh, ql, khb[l&1], klb[l&1], vhb[l&1], vlb[l&1], part);
    attn_combine<<<256,256,0,stream>>>(part, h, psum, psq);
    bn_apply2_kernel<<<512,256,0,stream>>>(h, psum, psq, bng + l*64, bnb + l*64);
  }
  final_kernel<<<3200,256,0,stream>>>(h, ow, ob, (float*)d_out);
}